// Round 6
// baseline (382.941 us; speedup 1.0000x reference)
//
#include <hip/hip_runtime.h>
#include <math.h>

// Problem shape (fixed by reference setup_inputs):
//   features:  (B=8, N=65536, C=64) fp32
//   coarse_map:(B=8, NP=16384, NS=32) int32 in [0, N)
//   out:       (B, NP, C) fp32 = max over NS gathered rows
constexpr int B  = 8;
constexpr int N  = 65536;
constexpr int C  = 64;      // floats per feature row (256 B)
constexpr int NP = 16384;
constexpr int NS = 32;
constexpr int C4 = C / 4;   // 16 float4 per row

// R6: R0/R4/R5 all pinned at ~3.7 TB/s & 128 us across three different
// schedules -> not a demand-side (MLP) limit. FETCH=432 MB vs 150 MB
// compulsory: features re-fetched ~3.2x because random order makes reuse
// distance = the whole dispatch. This round reduces reuse distance:
//   * 1024 fully-resident blocks; each 16-lane group owns 8 points.
//   * per point, bitonic-sort the 32 indices across the group's lanes
//     (max is order-invariant; any compare-exchange net = permutation,
//     so a sort bug cannot corrupt results).
//   * outer loop over 16 index bins (idx>>12) paces ALL blocks through
//     the feature table in the same order at the same time -> resident
//     working band ~8 MB instead of 134 MB -> L2/L3 catch the 8x reuse.
//   * cleanup pass consumes leftovers -> correctness independent of sort.

constexpr int NBIN = 16;
constexpr int PPG  = 8;     // points per 16-lane group
constexpr int GRID = 1024;  // blocks; 16 groups/block -> 16384 groups * 8 = 131072 pts

__device__ __forceinline__ int fetch_idx(int2 v, int pt, int gbase)
{
    // Group-uniform pt. Owner lane gbase + (pt>>1), slot = pt&1.
    const int sel = (pt & 1) ? v.y : v.x;
    return __shfl(sel, gbase + ((pt & 31) >> 1), 64);
}

__device__ __forceinline__ void gather_max(const float4* __restrict__ fbase,
                                           int idx, int j, float4& m)
{
    const float4 f = fbase[(size_t)idx * C4 + j];
    m.x = fmaxf(m.x, f.x);
    m.y = fmaxf(m.y, f.y);
    m.z = fmaxf(m.z, f.z);
    m.w = fmaxf(m.w, f.w);
}

__global__ __launch_bounds__(256, 4) void gather_max_kernel(
    const float4* __restrict__ feat,   // B*N*C4 float4
    const int*    __restrict__ cmap,   // B*NP*NS int32
    float4*       __restrict__ out)    // B*NP*C4 float4
{
    const int tid   = blockIdx.x * blockDim.x + threadIdx.x;
    const int group = tid >> 4;            // 0 .. 16383
    const int j     = tid & 15;            // float4 slot within the row
    const int lane  = threadIdx.x & 63;
    const int gbase = lane & ~15;

    const int point0 = group * PPG;        // 8 consecutive points, same batch
    const int b      = point0 >> 14;       // NP = 16384 = 2^14
    const float4* fbase = feat + (size_t)b * N * C4;

    // ---- load this group's 8 index lists (lane j holds idx[2j], idx[2j+1]) ----
    int2 my[PPG];
#pragma unroll
    for (int p = 0; p < PPG; ++p)
        my[p] = ((const int2*)(cmap + (size_t)(point0 + p) * NS))[j];

    // ---- bitonic sort each point's 32 indices across the 16 lanes ----
    // element e = 2*j + t; (e & k) == ((2*j) & k) for all k >= 2.
#pragma unroll
    for (int p = 0; p < PPG; ++p) {
        int a = my[p].x;                   // element 2j
        int c = my[p].y;                   // element 2j+1
#pragma unroll
        for (int k = 2; k <= 32; k <<= 1) {
#pragma unroll
            for (int jm = 16; jm > 0; jm >>= 1) {
                if (jm > (k >> 1)) continue;   // stages of this pass
                const bool up = (((2 * j) & k) == 0);
                if (jm == 1) {
                    // partner is the other slot of the same lane
                    const int lo = min(a, c), hi = max(a, c);
                    a = up ? lo : hi;
                    c = up ? hi : lo;
                } else {
                    const int lm = jm >> 1;            // lane xor mask (<16)
                    const int pa = __shfl_xor(a, lm, 64);
                    const int pc = __shfl_xor(c, lm, 64);
                    const bool low     = ((j & lm) == 0);
                    const bool keepmin = (up == low);
                    a = keepmin ? min(a, pa) : max(a, pa);
                    c = keepmin ? min(c, pc) : max(c, pc);
                }
            }
        }
        my[p].x = a;
        my[p].y = c;
    }

    // ---- paced consumption: all blocks walk bins 0..15 together ----
    float4 m[PPG];
    int    ptr[PPG];
#pragma unroll
    for (int p = 0; p < PPG; ++p) {
        m[p]   = make_float4(-INFINITY, -INFINITY, -INFINITY, -INFINITY);
        ptr[p] = 0;
    }

    for (int k = 0; k < NBIN; ++k) {       // runtime loop: shared pacing
#pragma unroll
        for (int p = 0; p < PPG; ++p) {
            int pt  = ptr[p];
            int cur = fetch_idx(my[p], pt, gbase);
            while (pt < NS && (cur >> 12) == k) {
                gather_max(fbase, cur, j, m[p]);
                ++pt;
                cur = fetch_idx(my[p], pt, gbase);
            }
            ptr[p] = pt;
        }
    }

    // ---- cleanup: processes leftovers if the sort were ever imperfect ----
#pragma unroll
    for (int p = 0; p < PPG; ++p) {
        int pt = ptr[p];
        while (pt < NS) {
            const int cur = fetch_idx(my[p], pt, gbase);
            gather_max(fbase, cur, j, m[p]);
            ++pt;
        }
    }

    // ---- coalesced stores: 256 B contiguous per point ----
#pragma unroll
    for (int p = 0; p < PPG; ++p)
        out[(size_t)(point0 + p) * C4 + j] = m[p];
}

extern "C" void kernel_launch(void* const* d_in, const int* in_sizes, int n_in,
                              void* d_out, int out_size, void* d_ws, size_t ws_size,
                              hipStream_t stream) {
    const float4* feat = (const float4*)d_in[0];
    const int*    cmap = (const int*)d_in[1];
    float4*       out  = (float4*)d_out;

    const int block = 256;
    gather_max_kernel<<<GRID, block, 0, stream>>>(feat, cmap, out);
}

// Round 7
// 290.402 us; speedup vs baseline: 1.3187x; 1.3187x over previous
//
#include <hip/hip_runtime.h>
#include <math.h>

// Problem shape (fixed by reference setup_inputs):
//   features:  (B=8, N=65536, C=64) fp32
//   coarse_map:(B=8, NP=16384, NS=32) int32 in [0, N)
//   out:       (B, NP, C) fp32 = max over NS gathered rows
constexpr int B  = 8;
constexpr int N  = 65536;
constexpr int C  = 64;      // floats per feature row (256 B)
constexpr int NP = 16384;
constexpr int NS = 32;
constexpr int C4 = C / 4;   // 16 float4 per row

// R7: R6 proved locality works (FETCH 432->373 MB) but its explicit bin
// pacing serialized the loads (BW 1.74 TB/s, VALU 37%). This round keeps
// the per-point index sort and DROPS the pacing: sorted-order consumption
// with a (near) fully-resident cohort is self-pacing -- at sample step t
// every wave reads near the t-th order statistic (band ~±0.7 MB/batch,
// ~30 MB instantaneous working set across 8 batches -> L3-resident).
// Consumption loop is exactly R0's (3.7 TB/s @ 7% VALU), fed from sorted
// register-resident indices. Sort = 15 shuffle stages; any compare-
// exchange network is a permutation and max is order-invariant, so
// correctness does not depend on the sort (R6: absmax 0.0).

constexpr int PPG  = 4;                         // points per 16-lane group
constexpr int GRID = (B * NP / PPG) * 16 / 256; // 2048 blocks, exact cover

__device__ __forceinline__ int fetch_idx(int2 v, int s, int gbase)
{
    // Owner lane gbase + (s>>1) holds sample s in slot (s&1).
    const int sel = (s & 1) ? v.y : v.x;
    return __shfl(sel, gbase + (s >> 1), 64);
}

// Bitonic sort of 32 ints distributed over 16 lanes (lane j holds elements
// 2j, 2j+1). Element e's direction bit uses (2j)&k, valid for k >= 2.
__device__ __forceinline__ int2 sort32(int2 v, int j)
{
    int a = v.x, c = v.y;
#pragma unroll
    for (int k = 2; k <= 32; k <<= 1) {
#pragma unroll
        for (int jm = 16; jm > 0; jm >>= 1) {
            if (jm > (k >> 1)) continue;       // stages of this pass
            const bool up = (((2 * j) & k) == 0);
            if (jm == 1) {
                const int lo = min(a, c), hi = max(a, c);
                a = up ? lo : hi;
                c = up ? hi : lo;
            } else {
                const int lm = jm >> 1;        // lane xor distance (<16)
                const int pa = __shfl_xor(a, lm, 64);
                const int pc = __shfl_xor(c, lm, 64);
                const bool keepmin = (up == ((j & lm) == 0));
                a = keepmin ? min(a, pa) : max(a, pa);
                c = keepmin ? min(c, pc) : max(c, pc);
            }
        }
    }
    return make_int2(a, c);
}

// 16 lanes cooperate on one output point; lane j owns channels [4j, 4j+4).
// Each gathered row read = 16 lanes x float4 = one contiguous 256 B segment.
__global__ __launch_bounds__(256, 4) void gather_max_kernel(
    const float4* __restrict__ feat,   // B*N*C4 float4
    const int*    __restrict__ cmap,   // B*NP*NS int32
    float4*       __restrict__ out)    // B*NP*C4 float4
{
    const int tid   = blockIdx.x * blockDim.x + threadIdx.x;
    const int group = tid >> 4;            // 0 .. 32767
    const int j     = tid & 15;            // float4 slot within the row
    const int lane  = threadIdx.x & 63;
    const int gbase = lane & ~15;          // base lane of this 16-lane group

    const int point0 = group * PPG;        // 4 consecutive points, same batch
    if (point0 >= B * NP) return;
    const int b = point0 >> 14;            // NP = 16384 = 2^14
    const float4* fbase = feat + (size_t)b * N * C4;

    // Load this group's 4 index lists (lane j holds idx[2j], idx[2j+1],
    // 128 B coalesced per point) and sort each in-register.
    int2 my[PPG];
#pragma unroll
    for (int p = 0; p < PPG; ++p)
        my[p] = ((const int2*)(cmap + (size_t)(point0 + p) * NS))[j];
#pragma unroll
    for (int p = 0; p < PPG; ++p)
        my[p] = sort32(my[p], j);

    // Consumption: identical structure to R0, but in ascending index order.
#pragma unroll
    for (int p = 0; p < PPG; ++p) {
        float4 m = make_float4(-INFINITY, -INFINITY, -INFINITY, -INFINITY);
#pragma unroll
        for (int s = 0; s < NS; ++s) {
            const int idx = fetch_idx(my[p], s, gbase);
            const float4 f = fbase[(size_t)idx * C4 + j];
            m.x = fmaxf(m.x, f.x);
            m.y = fmaxf(m.y, f.y);
            m.z = fmaxf(m.z, f.z);
            m.w = fmaxf(m.w, f.w);
        }
        // Coalesced float4 store: 256 B contiguous per point.
        out[(size_t)(point0 + p) * C4 + j] = m;
    }
}

extern "C" void kernel_launch(void* const* d_in, const int* in_sizes, int n_in,
                              void* d_out, int out_size, void* d_ws, size_t ws_size,
                              hipStream_t stream) {
    const float4* feat = (const float4*)d_in[0];
    const int*    cmap = (const int*)d_in[1];
    float4*       out  = (float4*)d_out;

    const int block = 256;
    gather_max_kernel<<<GRID, block, 0, stream>>>(feat, cmap, out);
}

// Round 8
// 274.973 us; speedup vs baseline: 1.3926x; 1.0561x over previous
//
#include <hip/hip_runtime.h>
#include <math.h>

// Problem shape (fixed by reference setup_inputs):
//   features:  (B=8, N=65536, C=64) fp32
//   coarse_map:(B=8, NP=16384, NS=32) int32 in [0, N)
//   out:       (B, NP, C) fp32 = max over NS gathered rows
constexpr int B  = 8;
constexpr int N  = 65536;
constexpr int C  = 64;      // floats per feature row (256 B)
constexpr int NP = 16384;
constexpr int NS = 32;
constexpr int C4 = C / 4;   // 16 float4 per row

typedef float f32x4 __attribute__((ext_vector_type(4)));

// R8 (= R2 rerun; R5 proved the R2/R3 container losses were infra, not the
// kernel): every compiler-mediated pipeline attempt left VGPR at 36-40 (the
// scheduler sinks loads to consumers -> ~0.6 loads in flight per thread ->
// Little's law: 14 KB/CU in flight / 0.97 us = 3.7 TB/s, exactly what we
// measure). Inline-asm global_load_dwordx4 makes 16 in-flight float4s
// architecturally unavoidable: the asm defines the output regs, the reduces
// consume them later, so the 64 VGPRs MUST stay live. Manual counted
// s_waitcnt vmcnt(8) (never 0 mid-loop) + sched_barrier(0) per rule #18.
// Decisive test: MLP artifact (dur -> ~80 us) vs service ceiling (dur flat).

#define WAITCNT_VM(n)                                         \
    do {                                                      \
        asm volatile("s_waitcnt vmcnt(" #n ")" ::: "memory"); \
        __builtin_amdgcn_sched_barrier(0);                    \
    } while (0)

template <int G>
__device__ __forceinline__ void issue_batch(const f32x4* __restrict__ fbase,
                                            int2 myIdx, int gbase, int j,
                                            f32x4 (&f)[8])
{
#pragma unroll
    for (int u = 0; u < 8; ++u) {
        const int s   = G * 8 + u;
        const int v   = (s & 1) ? myIdx.y : myIdx.x;
        const int idx = __shfl(v, gbase + (s >> 1), 64);
        const f32x4* p = fbase + (size_t)idx * C4 + j;
        asm volatile("global_load_dwordx4 %0, %1, off"
                     : "=v"(f[u]) : "v"(p));
    }
}

__device__ __forceinline__ void reduce_batch(const f32x4 (&f)[8], f32x4& m)
{
#pragma unroll
    for (int u = 0; u < 8; ++u) {
        m.x = fmaxf(m.x, f[u].x);
        m.y = fmaxf(m.y, f[u].y);
        m.z = fmaxf(m.z, f[u].z);
        m.w = fmaxf(m.w, f[u].w);
    }
}

// 16 lanes cooperate on one output point; lane j owns channels [4j, 4j+4).
// Each gathered row read = 16 lanes x float4 = one contiguous 256 B segment.
__global__ __launch_bounds__(256, 4) void gather_max_kernel(
    const f32x4* __restrict__ feat,   // B*N*C4 float4
    const int*   __restrict__ cmap,   // B*NP*NS int32
    f32x4*       __restrict__ out)    // B*NP*C4 float4
{
    const int tid   = blockIdx.x * blockDim.x + threadIdx.x;
    const int point = tid >> 4;            // global point id in [0, B*NP)
    const int j     = tid & 15;            // lane-within-group = float4 index
    if (point >= B * NP) return;

    const int    b     = point >> 14;      // point / NP (NP = 16384 = 2^14)
    const f32x4* fbase = feat + (size_t)b * N * C4;

    // Cooperative index load: lane j holds idx[2j], idx[2j+1] (coalesced 128 B/group).
    const int2 myIdx = ((const int2*)(cmap + (size_t)point * NS))[j];

    const int lane  = threadIdx.x & 63;
    const int gbase = lane & ~15;          // base lane of this 16-lane group

    f32x4 m = { -INFINITY, -INFINITY, -INFINITY, -INFINITY };

    f32x4 fA[8], fB[8];

    // Software pipeline over 4 batches of 8 samples, 2 batches in flight.
    issue_batch<0>(fbase, myIdx, gbase, j, fA);
    issue_batch<1>(fbase, myIdx, gbase, j, fB);

    WAITCNT_VM(8);                 // batch 0 landed (batch 1 still in flight)
    reduce_batch(fA, m);
    issue_batch<2>(fbase, myIdx, gbase, j, fA);

    WAITCNT_VM(8);                 // batch 1 landed (batch 2 in flight)
    reduce_batch(fB, m);
    issue_batch<3>(fbase, myIdx, gbase, j, fB);

    WAITCNT_VM(8);                 // batch 2 landed (batch 3 in flight)
    reduce_batch(fA, m);

    WAITCNT_VM(0);                 // batch 3 landed
    reduce_batch(fB, m);

    // Coalesced float4 store: consecutive lanes -> consecutive float4s.
    out[(size_t)point * C4 + j] = m;
}

extern "C" void kernel_launch(void* const* d_in, const int* in_sizes, int n_in,
                              void* d_out, int out_size, void* d_ws, size_t ws_size,
                              hipStream_t stream) {
    const f32x4* feat = (const f32x4*)d_in[0];
    const int*   cmap = (const int*)d_in[1];
    f32x4*       out  = (f32x4*)d_out;

    const int totalThreads = B * NP * 16;         // 16 lanes per point
    const int block = 256;
    const int grid  = (totalThreads + block - 1) / block;  // 8192
    gather_max_kernel<<<grid, block, 0, stream>>>(feat, cmap, out);
}